// Round 7
// baseline (1317.069 us; speedup 1.0000x reference)
//
#include <hip/hip_runtime.h>

// Correlation layer: out[b, dy*9+dx, y, x] =
//   (1/256) * sum_c frn[b,c,y,x] * fqn_pad[b,c,y+dy,x+dx]   (pad r=4)
// Identity: dot(frn,fqn) = dot(fr,fq) * invnorm(fr) * invnorm(fq).
//
// R14: R11 geometry VERBATIM (GD=3, CK=4, 1152 blocks x 1 wave, 154us
// best), staging switched global_load_lds -> T14 async-split reg staging.
// Why: R12 (2 waves/block) doubled per-chunk wall exactly (5775->12150cy)
// -- co-resident waves' stalls did NOT overlap, implicating a SHARED
// in-order per-CU return queue for global_load_lds: every wave's vmcnt
// drain waits behind all resident waves' DMA returns (fits R7 13.5-wave
// wall 7.1k, R11 4.5-wave 5.8k, R12 lockstep). R13 (CK=8) spilled
// (WRITE 183MB, VALU 13%) -- contaminated, reverted.
// This round: issue 7 plain global_load_dwordx4 -> regs for chunk n+1 at
// top of iter n; compute chunk n from buf[p] (~2000cy hides the loads);
// then 7 ds_write_b128 -> buf[1-p]. No global_load_lds, NO manual
// waitcnt anywhere: load->ds_write dep is register-carried (compiler
// emits exact vmcnt), DS ops are in-order per wave (ds_read after
// ds_write to same addr needs no wait; WAR across iters safe same way).
// sched_barrier(0) after the load cluster pins the prefetch early.
// Cost: +28 transient VGPR (stg[7]) -- spill sentinel is WRITE_SIZE.
// OOB halo lanes CLAMP-addressed (garbage data; masked at epilogue ==
// reference zero-pad). 1 wave/block, 0 barriers.

#define BB 8
#define CC 256
#define HH 96
#define WW 128
#define HW (HH*WW)
#define CHW (CC*HW)
#define NDISP 81
#define TYS 4            // output rows per block
#define GD 3             // dy per block
#define HROWS (TYS+GD-1) // 6 staged rows per chunk-channel
#define HX4 18           // halo row width in float4 (72 floats = 64 + 8)
#define NSLOT (HROWS*HX4) // 108 float4 slots per channel
#define CK 4             // channels per chunk
#define CKHW (CK*HW)
#define NCHK (CC/CK)     // 64 chunks
#define NST (NSLOT*CK)   // 432 float4 slots per chunk (6912 B/buffer)
#define YT (HH/TYS)      // 24
#define XT 2
#define NTILES (BB*YT*XT) // 384
#define NGRP 3           // dy-groups
#define EPSN 1e-12f

__global__ __launch_bounds__(64) __attribute__((amdgpu_waves_per_eu(2, 8)))
void corr_kernel(
    const float* __restrict__ fr, const float* __restrict__ fq,
    float* __restrict__ out)
{
    __shared__ float4 s_fq[2][NST];   // 13824 B, double-buffered fq halo chunk

    const int lane = threadIdx.x;
    const int tx   = lane & 15;    // 0..15, 4 px each
    const int ty   = lane >> 4;    // 0..3

    const int tile = blockIdx.x % NTILES;  // dyg-copies at stride 384 ≡ 0 mod 8 → same XCD
    const int dyg  = blockIdx.x / NTILES;  // 0..2 → dy = 3*dyg + g
    const int b    = tile / (YT * XT);
    const int rem  = tile % (YT * XT);
    const int y0   = (rem >> 1) * TYS;
    const int x0   = (rem & 1) * 64;

    // ---- staging addresses: slot i = 64j+lane -> (c=i/108, row=(i%108)/18, col4=i%18)
    // OOB rows/cols clamped to valid addresses (garbage data; masked at epilogue).
    int soff[7];
#pragma unroll
    for (int j = 0; j < 7; ++j) {
        int i = 64 * j + lane;
        int c    = (i / NSLOT) & 3;   // &3: j=6 upper lanes write nothing, keep addr safe
        int s    = i % NSLOT;
        int row  = s / HX4;
        int col4 = s % HX4;
        int gy = y0 + 3 * dyg - 4 + row;
        int gx = x0 - 4 + col4 * 4;
        gy = min(max(gy, 0), HH - 1);
        gx = min(max(gx, 0), WW - 4);   // stays 16B-aligned
        soff[j] = b * CHW + c * HW + gy * WW + gx;
    }

    const int frbase = b * CHW + (y0 + ty) * WW + x0 + tx * 4;

    // ---- preamble: chunk 0 -> regs -> buf0; fr chunk 0 -> regs
    float4 stg[7];
#pragma unroll
    for (int j = 0; j < 7; ++j)
        stg[j] = *(const float4*)(fq + soff[j]);
#pragma unroll
    for (int j = 0; j < 6; ++j)
        s_fq[0][64 * j + lane] = stg[j];
    if (lane < 48)                       // 48 tail slots (384..431)
        s_fq[0][384 + lane] = stg[6];

    float4 fra[CK];
#pragma unroll
    for (int c = 0; c < CK; ++c)
        fra[c] = *(const float4*)(fr + frbase + c * HW);

    float4 acc[GD][9];
#pragma unroll
    for (int g = 0; g < GD; ++g)
#pragma unroll
        for (int d = 0; d < 9; ++d) acc[g][d] = make_float4(0.f, 0.f, 0.f, 0.f);
    float sqn[GD][12];
#pragma unroll
    for (int g = 0; g < GD; ++g)
#pragma unroll
        for (int i = 0; i < 12; ++i) sqn[g][i] = 0.f;
    float4 fr2 = make_float4(0.f, 0.f, 0.f, 0.f);

#pragma unroll 1
    for (int ch = 0; ch < NCHK; ++ch) {
        const int p   = ch & 1;
        const int nch = (ch + 1 < NCHK) ? ch + 1 : ch;   // last iter: dead reload
        const int nco = nch * CKHW;

        // ---- issue next chunk's 7 loads into registers (prefetch) ----
#pragma unroll
        for (int j = 0; j < 7; ++j)
            stg[j] = *(const float4*)(fq + soff[j] + nco);
        __builtin_amdgcn_sched_barrier(0);    // keep the prefetch issued early

        // ---- compute 4 channels x 3 dy from buf p; roll fr one chunk ahead ----
#pragma unroll
        for (int c = 0; c < CK; ++c) {
            float4 a = fra[c];
            fra[c] = *(const float4*)(fr + frbase + nco + c * HW);
            fr2.x += a.x * a.x; fr2.y += a.y * a.y;
            fr2.z += a.z * a.z; fr2.w += a.w * a.w;

#pragma unroll
            for (int g = 0; g < GD; ++g) {
                float rw[12];
#pragma unroll
                for (int s4 = 0; s4 < 3; ++s4) {
                    float4 t = s_fq[p][c * NSLOT + (ty + g) * HX4 + tx + s4];
                    rw[s4 * 4 + 0] = t.x;
                    rw[s4 * 4 + 1] = t.y;
                    rw[s4 * 4 + 2] = t.z;
                    rw[s4 * 4 + 3] = t.w;
                }
#pragma unroll
                for (int i = 0; i < 12; ++i) sqn[g][i] += rw[i] * rw[i];
#pragma unroll
                for (int dx = 0; dx < 9; ++dx) {
                    acc[g][dx].x += a.x * rw[dx + 0];
                    acc[g][dx].y += a.y * rw[dx + 1];
                    acc[g][dx].z += a.z * rw[dx + 2];
                    acc[g][dx].w += a.w * rw[dx + 3];
                }
            }
        }

        // ---- write staged regs into the other buffer (DS in-order: the
        // next iteration's ds_reads need no explicit wait; WAR vs iter-1
        // reads safe the same way). Compiler inserts the exact vmcnt for
        // the stg register deps. Last iter: dead rewrite, never read. ----
#pragma unroll
        for (int j = 0; j < 6; ++j)
            s_fq[1 - p][64 * j + lane] = stg[j];
        if (lane < 48)
            s_fq[1 - p][384 + lane] = stg[6];
    }

    // ---- epilogue: norms in registers + OOB mask (== reference zero-pad) ----
    float4 ir;
    ir.x = 1.0f / fmaxf(sqrtf(fr2.x), EPSN);
    ir.y = 1.0f / fmaxf(sqrtf(fr2.y), EPSN);
    ir.z = 1.0f / fmaxf(sqrtf(fr2.z), EPSN);
    ir.w = 1.0f / fmaxf(sqrtf(fr2.w), EPSN);

    const int  xe0   = x0 + tx * 4;
    const float inv256 = 1.0f / 256.0f;

#pragma unroll
    for (int g = 0; g < GD; ++g) {
        const int dy = 3 * dyg + g;
        float inq[12];
#pragma unroll
        for (int i = 0; i < 12; ++i)
            inq[i] = 1.0f / fmaxf(sqrtf(sqn[g][i]), EPSN);

        const bool rowok = ((unsigned)(y0 + ty + dy - 4) < (unsigned)HH);
        const int obase = (b * NDISP + dy * 9) * HW + (y0 + ty) * WW + xe0;
#pragma unroll
        for (int dx = 0; dx < 9; ++dx) {
            float4 a = acc[g][dx];
            float4 o;
            o.x = a.x * ir.x * inq[dx + 0] * inv256;
            o.y = a.y * ir.y * inq[dx + 1] * inv256;
            o.z = a.z * ir.z * inq[dx + 2] * inv256;
            o.w = a.w * ir.w * inq[dx + 3] * inv256;
            const int cb = xe0 + dx - 4;   // fq column for px .x at this dx
            o.x = (rowok && (unsigned)(cb    ) < (unsigned)WW) ? o.x : 0.f;
            o.y = (rowok && (unsigned)(cb + 1) < (unsigned)WW) ? o.y : 0.f;
            o.z = (rowok && (unsigned)(cb + 2) < (unsigned)WW) ? o.z : 0.f;
            o.w = (rowok && (unsigned)(cb + 3) < (unsigned)WW) ? o.w : 0.f;
            *(float4*)(out + obase + dx * HW) = o;
        }
    }
}

extern "C" void kernel_launch(void* const* d_in, const int* in_sizes, int n_in,
                              void* d_out, int out_size, void* d_ws, size_t ws_size,
                              hipStream_t stream) {
    const float* fr = (const float*)d_in[0];
    const float* fq = (const float*)d_in[1];
    float* out = (float*)d_out;
    corr_kernel<<<dim3(NTILES * NGRP), dim3(64), 0, stream>>>(fr, fq, out);
}